// Round 11
// baseline (95323.535 us; speedup 1.0000x reference)
//
#include <hip/hip_runtime.h>
#include <math.h>

#define S_LEN 4096
#define HDIRC 256
#define NTAG 10
#define START_TAG 8
#define STOP_TAG 9
#define NEGV -10000.0f

// -------- workspace layout (float units) --------
#define XW_OFF 0UL
#define XW_SZ  (2UL * S_LEN * 1024)          // xw[dir][t][1024]
#define HS_OFF (XW_OFF + XW_SZ)
#define HS_SZ  (2UL * S_LEN * 256)           // hs[dir][t][256] (dir1 indexed by backward step)
#define WT_OFF (HS_OFF + HS_SZ)
#define WT_SZ  (2UL * 256 * 1024)            // WihT[dir][k][r]
#define FE_OFF (WT_OFF + WT_SZ)
#define FE_SZ  ((size_t)S_LEN * NTAG)        // feats[t][tag]
#define SLOW_OFF (FE_OFF + FE_SZ)            // 128B-aligned (all sizes mult of 32 floats)
#define SLOW_SZ (2UL * 2 * 256 * 2)          // u64 slow[dir][slot][dim], as floats
#define FAST_OFF (SLOW_OFF + SLOW_SZ)        // 128B-aligned
#define FAST_SZ (2UL * 2 * 256 * 2)          // u64 fast[dir][slot][dim], as floats

// ---------------- Wih transpose: [1024][256] -> [256][1024] ----------------
__global__ void transpose_wih(const float* __restrict__ wf,
                              const float* __restrict__ wb,
                              float* __restrict__ wT) {
    __shared__ float tile[32][33];
    const float* src = blockIdx.z ? wb : wf;
    float* dst = wT + (size_t)blockIdx.z * 256 * 1024;
    int x = blockIdx.x * 32 + threadIdx.x;   // k  (0..255)
    int y = blockIdx.y * 32 + threadIdx.y;   // r  (0..1023)
    tile[threadIdx.y][threadIdx.x] = src[y * 256 + x];
    __syncthreads();
    int ko = blockIdx.x * 32 + threadIdx.y;
    int ro = blockIdx.y * 32 + threadIdx.x;
    dst[(size_t)ko * 1024 + ro] = tile[threadIdx.x][threadIdx.y];
}

// ---------------- xW = emb[sent] @ Wih^T + (bih+bhh) ----------------
__global__ __launch_bounds__(256) void xw_gemm(
    const int* __restrict__ sent, const float* __restrict__ emb,
    const float* __restrict__ wT,
    const float* __restrict__ bih_f, const float* __restrict__ bhh_f,
    const float* __restrict__ bih_b, const float* __restrict__ bhh_b,
    float* __restrict__ xw) {
    int dir = blockIdx.y;
    int t0 = blockIdx.x * 16;
    int tid = threadIdx.x;
    __shared__ __align__(16) float xs[16][256];
    for (int i = 0; i < 16; ++i) {
        int t = t0 + i;
        int pos = dir ? (S_LEN - 1 - t) : t;
        int idx = sent[pos];
        xs[i][tid] = emb[(size_t)idx * 256 + tid];
    }
    __syncthreads();
    const float* w = wT + (size_t)dir * 256 * 1024;
    const float* bi = dir ? bih_b : bih_f;
    const float* bh = dir ? bhh_b : bhh_f;
    float4 bv;
    bv.x = bi[4 * tid + 0] + bh[4 * tid + 0];
    bv.y = bi[4 * tid + 1] + bh[4 * tid + 1];
    bv.z = bi[4 * tid + 2] + bh[4 * tid + 2];
    bv.w = bi[4 * tid + 3] + bh[4 * tid + 3];
    float4 acc[16];
#pragma unroll
    for (int i = 0; i < 16; ++i) acc[i] = bv;
    for (int k4 = 0; k4 < 64; ++k4) {
        float4 w0 = ((const float4*)(w + (size_t)(4 * k4 + 0) * 1024))[tid];
        float4 w1 = ((const float4*)(w + (size_t)(4 * k4 + 1) * 1024))[tid];
        float4 w2 = ((const float4*)(w + (size_t)(4 * k4 + 2) * 1024))[tid];
        float4 w3 = ((const float4*)(w + (size_t)(4 * k4 + 3) * 1024))[tid];
#pragma unroll
        for (int i = 0; i < 16; ++i) {
            float4 xv = *(const float4*)&xs[i][4 * k4];
            acc[i].x = fmaf(w0.x, xv.x, acc[i].x);
            acc[i].y = fmaf(w0.y, xv.x, acc[i].y);
            acc[i].z = fmaf(w0.z, xv.x, acc[i].z);
            acc[i].w = fmaf(w0.w, xv.x, acc[i].w);
            acc[i].x = fmaf(w1.x, xv.y, acc[i].x);
            acc[i].y = fmaf(w1.y, xv.y, acc[i].y);
            acc[i].z = fmaf(w1.z, xv.y, acc[i].z);
            acc[i].w = fmaf(w1.w, xv.y, acc[i].w);
            acc[i].x = fmaf(w2.x, xv.z, acc[i].x);
            acc[i].y = fmaf(w2.y, xv.z, acc[i].y);
            acc[i].z = fmaf(w2.z, xv.z, acc[i].z);
            acc[i].w = fmaf(w2.w, xv.z, acc[i].w);
            acc[i].x = fmaf(w3.x, xv.w, acc[i].x);
            acc[i].y = fmaf(w3.y, xv.w, acc[i].y);
            acc[i].z = fmaf(w3.z, xv.w, acc[i].z);
            acc[i].w = fmaf(w3.w, xv.w, acc[i].w);
        }
    }
#pragma unroll
    for (int i = 0; i < 16; ++i)
        ((float4*)(xw + ((size_t)dir * S_LEN + t0 + i) * 1024))[tid] = acc[i];
}

// ---------------- LSTM recurrence ----------------
// Wave-local barrier-free structure (r1/r2, correctness-verified in r2's
// bench) on the PROVEN r8 L2 fast ring. Ledger driving this design:
//   publish-before-poll + no stores in poll  -> 6.3ms (r0/r3/r5/r8)
//   any stores inside the poll loop          -> 10-13ms (r2/r6/r7/r9)
//   fast L2 ring works (r8: FETCH 166->25MB), fabric latency NOT the limit
// => the 3690cy/step is the r0 serial chain (2 barriers + single-wave
// combine with divergent libm). This version removes it:
//   wave wv owns dims 4wv..4wv+3 (16 rows split 4 lanes x 64 k); per step:
//   matvec (16 b128 broadcast reads from PRIVATE padded hb) -> 2x shfl_xor
//   k-reduce -> branch-free act (tanh(z)=2*sigmoid(2z)-1, one expf + one
//   div, no divergent dual libm path) -> 4 gate shfls -> c,h -> lanes<4
//   publish to L2 fast ring (sc0) BEFORE poll -> poll own 4 lines (sc0).
//   ZERO barriers in the loop; xw prefetch issued at loop TOP so the poll's
//   first vmcnt(0) doesn't eat its IC latency.
// Slow agent-scope fallback: gated at iter>=64 (~16k cy, far outside normal
// skew -- r9's threshold of 4 was inside it and fired every step). Fires
// only on true placement failure; two-generation publish (pk, pk_prev)
// preserves liveness (max skew 1 step); bounded worst case, no deadlock:
// a healthy-but-ahead wave that blocks a peer sticks at its OWN next poll
// within one step and then slow-publishes pk_prev = exactly the stamp the
// peer needs, into the slot the peer polls. Stale stamps across graph
// replays are exact-match-safe (prev run leaves 4095/4096; new run wants
// 1,2,...).
__global__ __launch_bounds__(256, 1) void lstm_rec(
    const float* __restrict__ whh_f, const float* __restrict__ whh_b,
    const float* __restrict__ xw, float* __restrict__ hs,
    unsigned long long* __restrict__ slowr, unsigned long long* __restrict__ fastr) {
    int bid = blockIdx.x;
    int xs8 = bid & 7;
    if (xs8 > 1) return;                 // 96 of 128 blocks exit immediately
    int dir = xs8;                       // dir0 -> XCD0, dir1 -> XCD1 (r8-proven)
    int b = bid >> 3;                    // 0..15
    int tid = threadIdx.x;
    int wv = tid >> 6;         // wave -> dims 4wv..4wv+3
    int l = tid & 63;
    int q = l >> 4;            // k-chunk 0..3 (64 floats each)
    int r = l & 15;
    int g = r >> 2;            // gate (0=i,1=f,2=g,3=o)
    int dl = r & 3;            // local dim

    const float* whh = dir ? whh_b : whh_f;
    int row = g * 256 + b * 16 + 4 * wv + dl;   // 0..1023
    float4 w[16];
#pragma unroll
    for (int i = 0; i < 16; ++i)
        w[i] = *(const float4*)(whh + (size_t)row * 256 + 64 * q + 4 * i);
#pragma unroll
    for (int i = 0; i < 16; ++i)
        asm volatile("" : "+v"(w[i].x), "+v"(w[i].y), "+v"(w[i].z), "+v"(w[i].w));

    const float* xwd = xw + (size_t)dir * S_LEN * 1024;
    float* hsd = hs + (size_t)dir * S_LEN * 256;
    unsigned long long* slowd = slowr + (size_t)dir * 512;  // [slot(2)][dim(256)]
    unsigned long long* fastd = fastr + (size_t)dir * 512;

    // per-wave private h buffer: chunk cc at [68*cc .. 68*cc+63] (pad 4 ->
    // the 4 broadcast b128 read addresses land on disjoint bank groups)
    __shared__ __align__(16) float hb[4][272];
    float* hbw = hb[wv];
    hbw[l] = 0.f; hbw[68 + l] = 0.f; hbw[136 + l] = 0.f; hbw[204 + l] = 0.f;
    const float4* hq = (const float4*)(hbw + 68 * q);

    float c = 0.f;                              // c for dim dl (16x redundant)
    unsigned long long pk = 0, pk_prev = 0;     // lanes l<4 only
    int hdim = b * 16 + 4 * wv + dl;
    float xw_cur = xwd[row];
    __syncthreads();

    for (int t = 0; t < S_LEN; ++t) {
        // early-issue next-step xw prefetch (IC-resident; completes under
        // this step's compute so the poll's vmcnt doesn't pay its latency)
        int tn = (t + 1 < S_LEN) ? t + 1 : t;
        float xw_next = xwd[(size_t)tn * 1024 + row];

        // ---- matvec partial: 64 FMAs over own k-quarter ----
        float4 acc = make_float4(0.f, 0.f, 0.f, 0.f);
#pragma unroll
        for (int i = 0; i < 16; ++i) {
            float4 h4 = hq[i];
            acc.x = fmaf(w[i].x, h4.x, acc.x);
            acc.y = fmaf(w[i].y, h4.y, acc.y);
            acc.z = fmaf(w[i].z, h4.z, acc.z);
            acc.w = fmaf(w[i].w, h4.w, acc.w);
        }
        float z = (acc.x + acc.y) + (acc.z + acc.w);
        z += __shfl_xor(z, 16, 64);             // k-reduce across q groups
        z += __shfl_xor(z, 32, 64);
        z += xw_cur;
        // branch-free activation: tanh(z) = 2*sigmoid(2z) - 1
        float zz = (g == 2) ? 2.f * z : z;
        float e = expf(-zz);
        float rr = 1.f / (1.f + e);
        float act = (g == 2) ? fmaf(2.f, rr, -1.f) : rr;
        int base = l & 48;                      // stay within own q group
        float ig = __shfl(act, base + dl, 64);
        float fg = __shfl(act, base + 4 + dl, 64);
        float gg = __shfl(act, base + 8 + dl, 64);
        float og = __shfl(act, base + 12 + dl, 64);
        c = fmaf(fg, c, ig * gg);
        float ec = expf(-2.f * c);              // tanh(c) same identity
        float th = fmaf(2.f, 1.f / (1.f + ec), -1.f);
        float h = og * th;

        unsigned long long* fsl = fastd + (size_t)(t & 1) * 256;
        unsigned long long* ssl = slowd + (size_t)(t & 1) * 256;
        unsigned long long* sslo = slowd + (size_t)((t & 1) ^ 1) * 256;
        unsigned int want = (unsigned int)(t + 1);
        // publish FIRST (fast L2 ring + hs archive); NO stores after this
        // until the poll succeeds (r9 lesson)
        if (l < 4) {
            pk = ((unsigned long long)want << 32) |
                 (unsigned long long)__float_as_uint(h);
            asm volatile("global_store_dwordx2 %0, %1, off sc0"
                         :: "v"(&fsl[hdim]), "v"(pk) : "memory");
            hsd[(size_t)t * 256 + hdim] = h;
        }
        // ---- poll: fast (sc0/L2) every iter; agent-scope fallback only
        // after 64 failed iters (true placement failure) ----
        unsigned long long v0, v1, v2, v3;
        const unsigned long long* p0 = &fsl[l];
        const unsigned long long* p1 = &fsl[l + 64];
        const unsigned long long* p2 = &fsl[l + 128];
        const unsigned long long* p3 = &fsl[l + 192];
        for (int iter = 0;; ++iter) {
            unsigned long long f0, f1, f2, f3;
            asm volatile(
                "global_load_dwordx2 %0, %4, off sc0\n\t"
                "global_load_dwordx2 %1, %5, off sc0\n\t"
                "global_load_dwordx2 %2, %6, off sc0\n\t"
                "global_load_dwordx2 %3, %7, off sc0\n\t"
                "s_waitcnt vmcnt(0)"
                : "=&v"(f0), "=&v"(f1), "=&v"(f2), "=&v"(f3)
                : "v"(p0), "v"(p1), "v"(p2), "v"(p3)
                : "memory");
            bool o0 = (unsigned int)(f0 >> 32) == want;
            bool o1 = (unsigned int)(f1 >> 32) == want;
            bool o2 = (unsigned int)(f2 >> 32) == want;
            bool o3 = (unsigned int)(f3 >> 32) == want;
            if (__all(o0 & o1 & o2 & o3)) { v0 = f0; v1 = f1; v2 = f2; v3 = f3; break; }
            if (iter >= 64 && (iter & 31) == 0) {
                // placement-failure fallback: two-generation lazy publish
                // (a stalled peer lags at most one step) + agent reads
                if (l < 4) {
                    __hip_atomic_store(&ssl[hdim], pk,
                                       __ATOMIC_RELAXED, __HIP_MEMORY_SCOPE_AGENT);
                    __hip_atomic_store(&sslo[hdim], pk_prev,
                                       __ATOMIC_RELAXED, __HIP_MEMORY_SCOPE_AGENT);
                }
                unsigned long long q0 = __hip_atomic_load(&ssl[l], __ATOMIC_RELAXED, __HIP_MEMORY_SCOPE_AGENT);
                unsigned long long q1 = __hip_atomic_load(&ssl[l + 64], __ATOMIC_RELAXED, __HIP_MEMORY_SCOPE_AGENT);
                unsigned long long q2 = __hip_atomic_load(&ssl[l + 128], __ATOMIC_RELAXED, __HIP_MEMORY_SCOPE_AGENT);
                unsigned long long q3 = __hip_atomic_load(&ssl[l + 192], __ATOMIC_RELAXED, __HIP_MEMORY_SCOPE_AGENT);
                if (!o0) f0 = q0;
                if (!o1) f1 = q1;
                if (!o2) f2 = q2;
                if (!o3) f3 = q3;
                o0 = (unsigned int)(f0 >> 32) == want;
                o1 = (unsigned int)(f1 >> 32) == want;
                o2 = (unsigned int)(f2 >> 32) == want;
                o3 = (unsigned int)(f3 >> 32) == want;
                if (__all(o0 & o1 & o2 & o3)) { v0 = f0; v1 = f1; v2 = f2; v3 = f3; break; }
            }
        }
        hbw[l] = __uint_as_float((unsigned int)v0);
        hbw[68 + l] = __uint_as_float((unsigned int)v1);
        hbw[136 + l] = __uint_as_float((unsigned int)v2);
        hbw[204 + l] = __uint_as_float((unsigned int)v3);
        pk_prev = pk;
        xw_cur = xw_next;
    }
}

// ---------------- feats = [h_f, h_b] @ W_out^T + b_out ----------------
__global__ __launch_bounds__(64) void feats_k(const float* __restrict__ hs,
                                              const float* __restrict__ wout,
                                              const float* __restrict__ bout,
                                              float* __restrict__ feats) {
    int t = blockIdx.x, tau = blockIdx.y, lane = threadIdx.x;
    const float* hf = hs + (size_t)t * 256;
    const float* hbk = hs + (size_t)S_LEN * 256 + (size_t)(S_LEN - 1 - t) * 256;
    const float* w = wout + (size_t)tau * 512;
    float s = 0.f;
#pragma unroll
    for (int m = 0; m < 4; ++m) s = fmaf(w[lane + 64 * m], hf[lane + 64 * m], s);
#pragma unroll
    for (int m = 0; m < 4; ++m) s = fmaf(w[256 + lane + 64 * m], hbk[lane + 64 * m], s);
#pragma unroll
    for (int off = 32; off > 0; off >>= 1) s += __shfl_down(s, off, 64);
    if (lane == 0) feats[(size_t)t * NTAG + tau] = s + bout[tau];
}

// ---------------- Viterbi (single wave; bp table + path in LDS) ----------------
__global__ __launch_bounds__(64) void viterbi_k(const float* __restrict__ feats,
                                                const float* __restrict__ trans,
                                                float* __restrict__ out) {
    __shared__ float fstage[128 * NTAG];
    __shared__ unsigned char bp[S_LEN * NTAG];
    __shared__ float path[S_LEN];
    __shared__ float fvbuf[NTAG];
    __shared__ float term[NTAG];
    int tid = threadIdx.x;
    float tr[NTAG];
    float trstop = 0.f;
    if (tid < NTAG) {
#pragma unroll
        for (int j = 0; j < NTAG; ++j) tr[j] = trans[tid * NTAG + j];
        trstop = trans[STOP_TAG * NTAG + tid];
    }
    float fv = (tid == START_TAG) ? 0.f : NEGV;
    for (int t0 = 0; t0 < S_LEN; t0 += 128) {
        __syncthreads();
        for (int i = tid; i < 128 * NTAG; i += 64) fstage[i] = feats[(size_t)t0 * NTAG + i];
        __syncthreads();
        for (int tt = 0; tt < 128; ++tt) {
            int t = t0 + tt;
            if (tid < NTAG) fvbuf[tid] = fv;
            __syncthreads();
            if (tid < NTAG) {
                float best = -3.4e38f; int bj = 0;
#pragma unroll
                for (int j = 0; j < NTAG; ++j) {
                    float v = fvbuf[j] + tr[j];
                    if (v > best) { best = v; bj = j; }
                }
                bp[t * NTAG + tid] = (unsigned char)bj;
                fv = best + fstage[tt * NTAG + tid];
            }
            __syncthreads();
        }
    }
    if (tid < NTAG) term[tid] = fv + trstop;
    __syncthreads();
    if (tid == 0) {
        float best = -3.4e38f; int bi = 0;
#pragma unroll
        for (int i = 0; i < NTAG; ++i) {
            float v = term[i];
            if (v > best) { best = v; bi = i; }
        }
        out[0] = best;
        int tag = bi;
        for (int t = S_LEN - 1; t >= 0; --t) {
            path[t] = (float)tag;
            tag = bp[t * NTAG + tag];
        }
    }
    __syncthreads();
    for (int i = tid; i < S_LEN; i += 64) out[1 + i] = path[i];
}

extern "C" void kernel_launch(void* const* d_in, const int* in_sizes, int n_in,
                              void* d_out, int out_size, void* d_ws, size_t ws_size,
                              hipStream_t stream) {
    const int* sent = (const int*)d_in[0];
    const float* emb = (const float*)d_in[1];
    const float* wih_f = (const float*)d_in[2];
    const float* whh_f = (const float*)d_in[3];
    const float* bih_f = (const float*)d_in[4];
    const float* bhh_f = (const float*)d_in[5];
    const float* wih_b = (const float*)d_in[6];
    const float* whh_b = (const float*)d_in[7];
    const float* bih_b = (const float*)d_in[8];
    const float* bhh_b = (const float*)d_in[9];
    const float* wout = (const float*)d_in[10];
    const float* bout = (const float*)d_in[11];
    const float* trans = (const float*)d_in[12];

    float* ws = (float*)d_ws;
    float* xw = ws + XW_OFF;
    float* hs = ws + HS_OFF;
    float* wT = ws + WT_OFF;
    float* fe = ws + FE_OFF;
    unsigned long long* slowr = (unsigned long long*)(ws + SLOW_OFF);
    unsigned long long* fastr = (unsigned long long*)(ws + FAST_OFF);

    hipLaunchKernelGGL(transpose_wih, dim3(8, 32, 2), dim3(32, 32), 0, stream,
                       wih_f, wih_b, wT);
    hipLaunchKernelGGL(xw_gemm, dim3(S_LEN / 16, 2), dim3(256), 0, stream,
                       sent, emb, wT, bih_f, bhh_f, bih_b, bhh_b, xw);
    hipLaunchKernelGGL(lstm_rec, dim3(128), dim3(256), 0, stream,
                       whh_f, whh_b, xw, hs, slowr, fastr);
    hipLaunchKernelGGL(feats_k, dim3(S_LEN, NTAG), dim3(64), 0, stream,
                       hs, wout, bout, fe);
    hipLaunchKernelGGL(viterbi_k, dim3(1), dim3(64), 0, stream,
                       fe, trans, (float*)d_out);
}

// Round 12
// 45664.737 us; speedup vs baseline: 2.0875x; 2.0875x over previous
//
#include <hip/hip_runtime.h>
#include <math.h>

#define S_LEN 4096
#define HDIRC 256
#define NTAG 10
#define START_TAG 8
#define STOP_TAG 9
#define NEGV -10000.0f

// -------- workspace layout (float units) --------
#define XW_OFF 0UL
#define XW_SZ  (2UL * S_LEN * 1024)          // xw[dir][t][1024]
#define HS_OFF (XW_OFF + XW_SZ)
#define HS_SZ  (2UL * S_LEN * 256)           // hs[dir][t][256] (dir1 indexed by backward step)
#define WT_OFF (HS_OFF + HS_SZ)
#define WT_SZ  (2UL * 256 * 1024)            // WihT[dir][k][r]
#define FE_OFF (WT_OFF + WT_SZ)
#define FE_SZ  ((size_t)S_LEN * NTAG)        // feats[t][tag]
#define SLOW_OFF (FE_OFF + FE_SZ)            // 128B-aligned (all sizes mult of 32 floats)
#define SLOW_SZ (2UL * 2 * 256 * 2)          // u64 slow[dir][slot][dim(256)], as floats
#define FAST_OFF (SLOW_OFF + SLOW_SZ)        // 128B-aligned
#define FAST_SZ (2UL * 2 * 1024 * 2)         // u64 fast[dir][slot][line(64)][16], as floats

// ---------------- Wih transpose: [1024][256] -> [256][1024] ----------------
__global__ void transpose_wih(const float* __restrict__ wf,
                              const float* __restrict__ wb,
                              float* __restrict__ wT) {
    __shared__ float tile[32][33];
    const float* src = blockIdx.z ? wb : wf;
    float* dst = wT + (size_t)blockIdx.z * 256 * 1024;
    int x = blockIdx.x * 32 + threadIdx.x;   // k  (0..255)
    int y = blockIdx.y * 32 + threadIdx.y;   // r  (0..1023)
    tile[threadIdx.y][threadIdx.x] = src[y * 256 + x];
    __syncthreads();
    int ko = blockIdx.x * 32 + threadIdx.y;
    int ro = blockIdx.y * 32 + threadIdx.x;
    dst[(size_t)ko * 1024 + ro] = tile[threadIdx.x][threadIdx.y];
}

// ---------------- xW = emb[sent] @ Wih^T + (bih+bhh) ----------------
__global__ __launch_bounds__(256) void xw_gemm(
    const int* __restrict__ sent, const float* __restrict__ emb,
    const float* __restrict__ wT,
    const float* __restrict__ bih_f, const float* __restrict__ bhh_f,
    const float* __restrict__ bih_b, const float* __restrict__ bhh_b,
    float* __restrict__ xw) {
    int dir = blockIdx.y;
    int t0 = blockIdx.x * 16;
    int tid = threadIdx.x;
    __shared__ __align__(16) float xs[16][256];
    for (int i = 0; i < 16; ++i) {
        int t = t0 + i;
        int pos = dir ? (S_LEN - 1 - t) : t;
        int idx = sent[pos];
        xs[i][tid] = emb[(size_t)idx * 256 + tid];
    }
    __syncthreads();
    const float* w = wT + (size_t)dir * 256 * 1024;
    const float* bi = dir ? bih_b : bih_f;
    const float* bh = dir ? bhh_b : bhh_f;
    float4 bv;
    bv.x = bi[4 * tid + 0] + bh[4 * tid + 0];
    bv.y = bi[4 * tid + 1] + bh[4 * tid + 1];
    bv.z = bi[4 * tid + 2] + bh[4 * tid + 2];
    bv.w = bi[4 * tid + 3] + bh[4 * tid + 3];
    float4 acc[16];
#pragma unroll
    for (int i = 0; i < 16; ++i) acc[i] = bv;
    for (int k4 = 0; k4 < 64; ++k4) {
        float4 w0 = ((const float4*)(w + (size_t)(4 * k4 + 0) * 1024))[tid];
        float4 w1 = ((const float4*)(w + (size_t)(4 * k4 + 1) * 1024))[tid];
        float4 w2 = ((const float4*)(w + (size_t)(4 * k4 + 2) * 1024))[tid];
        float4 w3 = ((const float4*)(w + (size_t)(4 * k4 + 3) * 1024))[tid];
#pragma unroll
        for (int i = 0; i < 16; ++i) {
            float4 xv = *(const float4*)&xs[i][4 * k4];
            acc[i].x = fmaf(w0.x, xv.x, acc[i].x);
            acc[i].y = fmaf(w0.y, xv.x, acc[i].y);
            acc[i].z = fmaf(w0.z, xv.x, acc[i].z);
            acc[i].w = fmaf(w0.w, xv.x, acc[i].w);
            acc[i].x = fmaf(w1.x, xv.y, acc[i].x);
            acc[i].y = fmaf(w1.y, xv.y, acc[i].y);
            acc[i].z = fmaf(w1.z, xv.y, acc[i].z);
            acc[i].w = fmaf(w1.w, xv.y, acc[i].w);
            acc[i].x = fmaf(w2.x, xv.z, acc[i].x);
            acc[i].y = fmaf(w2.y, xv.z, acc[i].y);
            acc[i].z = fmaf(w2.z, xv.z, acc[i].z);
            acc[i].w = fmaf(w2.w, xv.z, acc[i].w);
            acc[i].x = fmaf(w3.x, xv.w, acc[i].x);
            acc[i].y = fmaf(w3.y, xv.w, acc[i].y);
            acc[i].z = fmaf(w3.z, xv.w, acc[i].z);
            acc[i].w = fmaf(w3.w, xv.w, acc[i].w);
        }
    }
#pragma unroll
    for (int i = 0; i < 16; ++i)
        ((float4*)(xw + ((size_t)dir * S_LEN + t0 + i) * 1024))[tid] = acc[i];
}

// ---------------- LSTM recurrence ----------------
// r11's barrier-free wave-local structure with the fast-ring publish made a
// FULL-LINE store. r11 post-mortem: fast polls NEVER hit (53kcy/step, all
// slow-fallback) while r8's identical ring ALWAYS hit. Difference: r8
// published 16 lanes x 8B = 128B full line; r11 published 4 lanes x 8B = 32B
// partial line. Theory: full-line sc0 write-through stores install/update
// the L2 line (no fill needed); partial-line stores write AROUND L2,
// leaving any clean cached copy stale -> consumers poll stale data forever.
// Fix: one exclusive 128B line PER WAVE: fast[dir][slot][line=b*4+wv][16],
// entries = the wave's 4 dims replicated 4x (lanes l<16 all hold valid h
// for dim l&3 since h is redundant across the 4 gate groups). Publish =
// 16-lane 128B single-owner full-line store (the r8-proven pattern).
// Poll: dim l+64i lives at fsl[(l>>2)*16 + (l&3) + 256*i].
// Everything else as r11: zero barriers, branch-free act, publish-before-
// poll, no stores inside the poll; agent-scope fallback gated at iter>=32
// (healthy skew <= ~5 iters), recheck every 8 (bounds placement-failure
// worst case at ~15ms). Liveness/overwrite safety: per-wave r0 induction +
// two-generation lazy slow publish (unchanged from r11, which passed).
__global__ __launch_bounds__(256, 1) void lstm_rec(
    const float* __restrict__ whh_f, const float* __restrict__ whh_b,
    const float* __restrict__ xw, float* __restrict__ hs,
    unsigned long long* __restrict__ slowr, unsigned long long* __restrict__ fastr) {
    int bid = blockIdx.x;
    int xs8 = bid & 7;
    if (xs8 > 1) return;                 // 96 of 128 blocks exit immediately
    int dir = xs8;                       // dir0 -> XCD0, dir1 -> XCD1 (r8-proven)
    int b = bid >> 3;                    // 0..15
    int tid = threadIdx.x;
    int wv = tid >> 6;         // wave -> dims 4wv..4wv+3
    int l = tid & 63;
    int q = l >> 4;            // k-chunk 0..3 (64 floats each)
    int r = l & 15;
    int g = r >> 2;            // gate (0=i,1=f,2=g,3=o)
    int dl = r & 3;            // local dim

    const float* whh = dir ? whh_b : whh_f;
    int row = g * 256 + b * 16 + 4 * wv + dl;   // 0..1023
    float4 w[16];
#pragma unroll
    for (int i = 0; i < 16; ++i)
        w[i] = *(const float4*)(whh + (size_t)row * 256 + 64 * q + 4 * i);
#pragma unroll
    for (int i = 0; i < 16; ++i)
        asm volatile("" : "+v"(w[i].x), "+v"(w[i].y), "+v"(w[i].z), "+v"(w[i].w));

    const float* xwd = xw + (size_t)dir * S_LEN * 1024;
    float* hsd = hs + (size_t)dir * S_LEN * 256;
    unsigned long long* slowd = slowr + (size_t)dir * 512;   // [slot(2)][dim(256)]
    unsigned long long* fastd = fastr + (size_t)dir * 2048;  // [slot(2)][line(64)][16]

    // per-wave private h buffer: chunk cc at [68*cc .. 68*cc+63] (pad 4 ->
    // the 4 broadcast b128 read addresses land on disjoint bank groups)
    __shared__ __align__(16) float hb[4][272];
    float* hbw = hb[wv];
    hbw[l] = 0.f; hbw[68 + l] = 0.f; hbw[136 + l] = 0.f; hbw[204 + l] = 0.f;
    const float4* hq = (const float4*)(hbw + 68 * q);

    float c = 0.f;                              // c for dim dl (16x redundant)
    unsigned long long pk = 0, pk_prev = 0;
    int hdim = b * 16 + 4 * wv + dl;
    int pollb = (l >> 2) * 16 + (l & 3);        // fast addr base for dim l
    float xw_cur = xwd[row];
    __syncthreads();

    for (int t = 0; t < S_LEN; ++t) {
        // early-issue next-step xw prefetch (completes under this step's
        // compute so the poll's vmcnt doesn't pay its latency)
        int tn = (t + 1 < S_LEN) ? t + 1 : t;
        float xw_next = xwd[(size_t)tn * 1024 + row];

        // ---- matvec partial: 64 FMAs over own k-quarter ----
        float4 acc = make_float4(0.f, 0.f, 0.f, 0.f);
#pragma unroll
        for (int i = 0; i < 16; ++i) {
            float4 h4 = hq[i];
            acc.x = fmaf(w[i].x, h4.x, acc.x);
            acc.y = fmaf(w[i].y, h4.y, acc.y);
            acc.z = fmaf(w[i].z, h4.z, acc.z);
            acc.w = fmaf(w[i].w, h4.w, acc.w);
        }
        float z = (acc.x + acc.y) + (acc.z + acc.w);
        z += __shfl_xor(z, 16, 64);             // k-reduce across q groups
        z += __shfl_xor(z, 32, 64);
        z += xw_cur;
        // branch-free activation: tanh(z) = 2*sigmoid(2z) - 1
        float zz = (g == 2) ? 2.f * z : z;
        float e = expf(-zz);
        float rr = 1.f / (1.f + e);
        float act = (g == 2) ? fmaf(2.f, rr, -1.f) : rr;
        int base = l & 48;                      // stay within own q group
        float ig = __shfl(act, base + dl, 64);
        float fg = __shfl(act, base + 4 + dl, 64);
        float gg = __shfl(act, base + 8 + dl, 64);
        float og = __shfl(act, base + 12 + dl, 64);
        c = fmaf(fg, c, ig * gg);
        float ec = expf(-2.f * c);              // tanh(c) same identity
        float th = fmaf(2.f, 1.f / (1.f + ec), -1.f);
        float h = og * th;

        unsigned long long* fsl = fastd + (size_t)(t & 1) * 1024;
        unsigned long long* ssl = slowd + (size_t)(t & 1) * 256;
        unsigned long long* sslo = slowd + (size_t)((t & 1) ^ 1) * 256;
        unsigned int want = (unsigned int)(t + 1);
        pk = ((unsigned long long)want << 32) |
             (unsigned long long)__float_as_uint(h);
        // publish FIRST: FULL-LINE store -- 16 lanes x 8B into this wave's
        // exclusive 128B line (dims replicated 4x). NO stores after this
        // until the poll succeeds (r9 lesson).
        if (l < 16) {
            unsigned long long* fline = fsl + (size_t)(b * 4 + wv) * 16;
            asm volatile("global_store_dwordx2 %0, %1, off sc0"
                         :: "v"(&fline[l]), "v"(pk) : "memory");
        }
        if (l < 4) hsd[(size_t)t * 256 + hdim] = h;
        // ---- poll: fast (sc0/L2) every iter; agent-scope fallback only
        // after 32 failed iters (true placement failure), recheck every 8 ----
        unsigned long long v0, v1, v2, v3;
        const unsigned long long* p0 = fsl + pollb;
        const unsigned long long* p1 = fsl + pollb + 256;
        const unsigned long long* p2 = fsl + pollb + 512;
        const unsigned long long* p3 = fsl + pollb + 768;
        for (int iter = 0;; ++iter) {
            unsigned long long f0, f1, f2, f3;
            asm volatile(
                "global_load_dwordx2 %0, %4, off sc0\n\t"
                "global_load_dwordx2 %1, %5, off sc0\n\t"
                "global_load_dwordx2 %2, %6, off sc0\n\t"
                "global_load_dwordx2 %3, %7, off sc0\n\t"
                "s_waitcnt vmcnt(0)"
                : "=&v"(f0), "=&v"(f1), "=&v"(f2), "=&v"(f3)
                : "v"(p0), "v"(p1), "v"(p2), "v"(p3)
                : "memory");
            bool o0 = (unsigned int)(f0 >> 32) == want;
            bool o1 = (unsigned int)(f1 >> 32) == want;
            bool o2 = (unsigned int)(f2 >> 32) == want;
            bool o3 = (unsigned int)(f3 >> 32) == want;
            if (__all(o0 & o1 & o2 & o3)) { v0 = f0; v1 = f1; v2 = f2; v3 = f3; break; }
            if (iter >= 32 && (iter & 7) == 0) {
                // placement-failure fallback: two-generation lazy publish
                // (a stalled peer lags at most one step) + agent reads
                if (l < 4) {
                    __hip_atomic_store(&ssl[hdim], pk,
                                       __ATOMIC_RELAXED, __HIP_MEMORY_SCOPE_AGENT);
                    __hip_atomic_store(&sslo[hdim], pk_prev,
                                       __ATOMIC_RELAXED, __HIP_MEMORY_SCOPE_AGENT);
                }
                unsigned long long q0 = __hip_atomic_load(&ssl[l], __ATOMIC_RELAXED, __HIP_MEMORY_SCOPE_AGENT);
                unsigned long long q1 = __hip_atomic_load(&ssl[l + 64], __ATOMIC_RELAXED, __HIP_MEMORY_SCOPE_AGENT);
                unsigned long long q2 = __hip_atomic_load(&ssl[l + 128], __ATOMIC_RELAXED, __HIP_MEMORY_SCOPE_AGENT);
                unsigned long long q3 = __hip_atomic_load(&ssl[l + 192], __ATOMIC_RELAXED, __HIP_MEMORY_SCOPE_AGENT);
                if (!o0) f0 = q0;
                if (!o1) f1 = q1;
                if (!o2) f2 = q2;
                if (!o3) f3 = q3;
                o0 = (unsigned int)(f0 >> 32) == want;
                o1 = (unsigned int)(f1 >> 32) == want;
                o2 = (unsigned int)(f2 >> 32) == want;
                o3 = (unsigned int)(f3 >> 32) == want;
                if (__all(o0 & o1 & o2 & o3)) { v0 = f0; v1 = f1; v2 = f2; v3 = f3; break; }
            }
        }
        hbw[l] = __uint_as_float((unsigned int)v0);
        hbw[68 + l] = __uint_as_float((unsigned int)v1);
        hbw[136 + l] = __uint_as_float((unsigned int)v2);
        hbw[204 + l] = __uint_as_float((unsigned int)v3);
        pk_prev = pk;
        xw_cur = xw_next;
    }
}

// ---------------- feats = [h_f, h_b] @ W_out^T + b_out ----------------
__global__ __launch_bounds__(64) void feats_k(const float* __restrict__ hs,
                                              const float* __restrict__ wout,
                                              const float* __restrict__ bout,
                                              float* __restrict__ feats) {
    int t = blockIdx.x, tau = blockIdx.y, lane = threadIdx.x;
    const float* hf = hs + (size_t)t * 256;
    const float* hbk = hs + (size_t)S_LEN * 256 + (size_t)(S_LEN - 1 - t) * 256;
    const float* w = wout + (size_t)tau * 512;
    float s = 0.f;
#pragma unroll
    for (int m = 0; m < 4; ++m) s = fmaf(w[lane + 64 * m], hf[lane + 64 * m], s);
#pragma unroll
    for (int m = 0; m < 4; ++m) s = fmaf(w[256 + lane + 64 * m], hbk[lane + 64 * m], s);
#pragma unroll
    for (int off = 32; off > 0; off >>= 1) s += __shfl_down(s, off, 64);
    if (lane == 0) feats[(size_t)t * NTAG + tau] = s + bout[tau];
}

// ---------------- Viterbi (single wave; bp table + path in LDS) ----------------
__global__ __launch_bounds__(64) void viterbi_k(const float* __restrict__ feats,
                                                const float* __restrict__ trans,
                                                float* __restrict__ out) {
    __shared__ float fstage[128 * NTAG];
    __shared__ unsigned char bp[S_LEN * NTAG];
    __shared__ float path[S_LEN];
    __shared__ float fvbuf[NTAG];
    __shared__ float term[NTAG];
    int tid = threadIdx.x;
    float tr[NTAG];
    float trstop = 0.f;
    if (tid < NTAG) {
#pragma unroll
        for (int j = 0; j < NTAG; ++j) tr[j] = trans[tid * NTAG + j];
        trstop = trans[STOP_TAG * NTAG + tid];
    }
    float fv = (tid == START_TAG) ? 0.f : NEGV;
    for (int t0 = 0; t0 < S_LEN; t0 += 128) {
        __syncthreads();
        for (int i = tid; i < 128 * NTAG; i += 64) fstage[i] = feats[(size_t)t0 * NTAG + i];
        __syncthreads();
        for (int tt = 0; tt < 128; ++tt) {
            int t = t0 + tt;
            if (tid < NTAG) fvbuf[tid] = fv;
            __syncthreads();
            if (tid < NTAG) {
                float best = -3.4e38f; int bj = 0;
#pragma unroll
                for (int j = 0; j < NTAG; ++j) {
                    float v = fvbuf[j] + tr[j];
                    if (v > best) { best = v; bj = j; }
                }
                bp[t * NTAG + tid] = (unsigned char)bj;
                fv = best + fstage[tt * NTAG + tid];
            }
            __syncthreads();
        }
    }
    if (tid < NTAG) term[tid] = fv + trstop;
    __syncthreads();
    if (tid == 0) {
        float best = -3.4e38f; int bi = 0;
#pragma unroll
        for (int i = 0; i < NTAG; ++i) {
            float v = term[i];
            if (v > best) { best = v; bi = i; }
        }
        out[0] = best;
        int tag = bi;
        for (int t = S_LEN - 1; t >= 0; --t) {
            path[t] = (float)tag;
            tag = bp[t * NTAG + tag];
        }
    }
    __syncthreads();
    for (int i = tid; i < S_LEN; i += 64) out[1 + i] = path[i];
}

extern "C" void kernel_launch(void* const* d_in, const int* in_sizes, int n_in,
                              void* d_out, int out_size, void* d_ws, size_t ws_size,
                              hipStream_t stream) {
    const int* sent = (const int*)d_in[0];
    const float* emb = (const float*)d_in[1];
    const float* wih_f = (const float*)d_in[2];
    const float* whh_f = (const float*)d_in[3];
    const float* bih_f = (const float*)d_in[4];
    const float* bhh_f = (const float*)d_in[5];
    const float* wih_b = (const float*)d_in[6];
    const float* whh_b = (const float*)d_in[7];
    const float* bih_b = (const float*)d_in[8];
    const float* bhh_b = (const float*)d_in[9];
    const float* wout = (const float*)d_in[10];
    const float* bout = (const float*)d_in[11];
    const float* trans = (const float*)d_in[12];

    float* ws = (float*)d_ws;
    float* xw = ws + XW_OFF;
    float* hs = ws + HS_OFF;
    float* wT = ws + WT_OFF;
    float* fe = ws + FE_OFF;
    unsigned long long* slowr = (unsigned long long*)(ws + SLOW_OFF);
    unsigned long long* fastr = (unsigned long long*)(ws + FAST_OFF);

    hipLaunchKernelGGL(transpose_wih, dim3(8, 32, 2), dim3(32, 32), 0, stream,
                       wih_f, wih_b, wT);
    hipLaunchKernelGGL(xw_gemm, dim3(S_LEN / 16, 2), dim3(256), 0, stream,
                       sent, emb, wT, bih_f, bhh_f, bih_b, bhh_b, xw);
    hipLaunchKernelGGL(lstm_rec, dim3(128), dim3(256), 0, stream,
                       whh_f, whh_b, xw, hs, slowr, fastr);
    hipLaunchKernelGGL(feats_k, dim3(S_LEN, NTAG), dim3(64), 0, stream,
                       hs, wout, bout, fe);
    hipLaunchKernelGGL(viterbi_k, dim3(1), dim3(64), 0, stream,
                       fe, trans, (float*)d_out);
}